// Round 3
// baseline (362.980 us; speedup 1.0000x reference)
//
#include <hip/hip_runtime.h>

#define N_NODES 50000
#define N_EDGES 800000
#define FEAT 64
#define HID 128
#define N_TYPES 4
#define N_REL 3
#define N_LAYERS 2
#define LN_EPS 1e-5f
#define NROWS 50016   // 50000 padded to 32 (1563 groups of 32)
#define NG32 1563
#define CAP 64        // per-dst bucket capacity
#define NBKT 196      // coarse buckets: dst>>8
#define CAP1 4608     // coarse bucket capacity (mean 4082, +8 sigma)
#define EPB 4096      // edges per bin1 block
#define BINCAP 56     // per-block per-bin LDS capacity (mean 20.9, +7.7 sigma)
#define NCOMBO 400    // 100 z-values x 4 types
#define WT_STRIDE 136

typedef __attribute__((ext_vector_type(8))) short bf16x8;
typedef __attribute__((ext_vector_type(16))) float f32x16;
typedef __attribute__((ext_vector_type(2))) float f32x2;

static __device__ inline unsigned short f2bf(float f) {
    unsigned int u = __float_as_uint(f);
    return (unsigned short)((u + 0x7fffu + ((u >> 16) & 1u)) >> 16);
}
static __device__ inline unsigned int packbf2(float lo, float hi) {
    return (unsigned int)f2bf(lo) | ((unsigned int)f2bf(hi) << 16);
}

// decode 8 fp8-e4m3 (uint2) -> accumulate into a[0..7]
static __device__ inline void acc8_fp8(float* a, uint2 w) {
    f32x2 d0 = __builtin_amdgcn_cvt_pk_f32_fp8((int)w.x, false);
    f32x2 d1 = __builtin_amdgcn_cvt_pk_f32_fp8((int)w.x, true);
    f32x2 d2 = __builtin_amdgcn_cvt_pk_f32_fp8((int)w.y, false);
    f32x2 d3 = __builtin_amdgcn_cvt_pk_f32_fp8((int)w.y, true);
    a[0] += d0[0]; a[1] += d0[1]; a[2] += d1[0]; a[3] += d1[1];
    a[4] += d2[0]; a[5] += d2[1]; a[6] += d3[0]; a[7] += d3[1];
}

// ---------------------------------------------------------------------------
// MERGED front-end: blocks [0,196) = edge binning (+combo), [196,596) =
// encoder/layer-1 tables, [596,852) = layer-2 weight prep + pooled zero.
__global__ __launch_bounds__(256) void build_tables_kernel(
    const int* __restrict__ src, const int* __restrict__ dst,
    const int* __restrict__ et, const int* __restrict__ z,
    const int* __restrict__ nt,
    const float* __restrict__ z_embed, const float* __restrict__ w1,
    const float* __restrict__ b1, const float* __restrict__ w2,
    const float* __restrict__ b2, const float* __restrict__ rel_w,
    const float* __restrict__ lin_w, const float* __restrict__ lin_b,
    unsigned short* __restrict__ combo, int* __restrict__ bcnt,
    int* __restrict__ bucket, unsigned int* __restrict__ ytab,
    float* __restrict__ lintab, unsigned short* __restrict__ wbuf,
    float* __restrict__ pooled) {
    __shared__ int lbin[NBKT * BINCAP];  // 43.9 KB (bin1 branch only)
    __shared__ int lcnt[NBKT];
    __shared__ int lbase[NBKT];
    __shared__ float h[HID];             // encoder branch only
    __shared__ float xrow[HID];
    __shared__ float tmp[HID];

    int b = blockIdx.x;
    if (b < NBKT) {
        // ---- bin1: bin edges by dst>>8. Packed: src|et<<16|(dst&255)<<18 ----
        int ci = b * 256 + threadIdx.x;
        if (ci < N_NODES) combo[ci] = (unsigned short)(z[ci] * 4 + nt[ci]);
        for (int i = threadIdx.x; i < NBKT; i += 256) lcnt[i] = 0;
        __syncthreads();
        int base = b * EPB;
#pragma unroll
        for (int i = 0; i < EPB / 256; ++i) {
            int e = base + i * 256 + threadIdx.x;
            if (e < N_EDGES) {
                int d = dst[e];
                int bk = d >> 8;
                int v = src[e] | (et[e] << 16) | ((d & 255) << 18);
                int pos = atomicAdd(&lcnt[bk], 1);
                if (pos < BINCAP) lbin[bk * BINCAP + pos] = v;
            }
        }
        __syncthreads();
        if (threadIdx.x < NBKT) {
            int c = min(lcnt[threadIdx.x], BINCAP);
            lcnt[threadIdx.x] = c;
            lbase[threadIdx.x] = atomicAdd(&bcnt[threadIdx.x], c);
        }
        __syncthreads();
        int wv = threadIdx.x >> 6, ln = threadIdx.x & 63;
        for (int bb = wv; bb < NBKT; bb += 4) {
            int c = lcnt[bb];
            if (ln < c) {
                int gp = lbase[bb] + ln;
                if (gp < CAP1) bucket[bb * CAP1 + gp] = lbin[bb * BINCAP + ln];
            }
        }
        return;
    }
    if (b >= NBKT + NCOMBO) {
        // ---- weight prep for layer 2: 256 blocks x 256 threads = 65536 ----
        int pb = b - (NBKT + NCOMBO);
        if (pb == 0 && threadIdx.x < HID) pooled[threadIdx.x] = 0.0f;
        int idx = pb * 256 + threadIdx.x;
        int k = idx & 127;
        int col = (idx >> 7) & 127;
        int mat = idx >> 14;
        float w = (mat < 3) ? rel_w[(((size_t)(3 + mat)) * HID + k) * HID + col]
                            : lin_w[((size_t)(HID + k)) * HID + col];
        wbuf[(size_t)mat * HID * WT_STRIDE + col * WT_STRIDE + k] = f2bf(w);
        return;
    }
    // ---- encoder + layer-1 tables (one combo per block; threads<128 act) ----
    int c = b - NBKT;  // 0..399
    int zi = c >> 2;
    int t = c & 3;
    int j = threadIdx.x;
    bool act = j < HID;
    if (act) {
        float acc = b1[t * HID + j];
#pragma unroll 8
        for (int k = 0; k < FEAT; ++k)
            acc = fmaf(z_embed[zi * FEAT + k], w1[((size_t)t * FEAT + k) * HID + j], acc);
        h[j] = fmaxf(acc, 0.0f);
    }
    __syncthreads();
    if (act) {
        float acc2 = b2[t * HID + j];
#pragma unroll 8
        for (int k = 0; k < HID; ++k)
            acc2 = fmaf(h[k], w2[(size_t)t * HID * HID + k * HID + j], acc2);
        xrow[j] = acc2;
    }
    __syncthreads();
#pragma unroll 1
    for (int r = 0; r < N_REL; ++r) {
        if (act) {
            float a = 0.f;
            const float* W = rel_w + (size_t)r * HID * HID;  // layer 0
#pragma unroll 8
            for (int k = 0; k < HID; ++k) a = fmaf(xrow[k], W[k * HID + j], a);
            tmp[j] = a;
        }
        __syncthreads();
        if (j < 32) {  // pack 4 fp8 per uint
            int w0 = __builtin_amdgcn_cvt_pk_fp8_f32(tmp[4 * j], tmp[4 * j + 1], 0, false);
            w0 = __builtin_amdgcn_cvt_pk_fp8_f32(tmp[4 * j + 2], tmp[4 * j + 3], w0, true);
            ytab[(r * NCOMBO + c) * 32 + j] = (unsigned)w0;
        }
        __syncthreads();
    }
    if (act) {
        float a = lin_b[j];
#pragma unroll 8
        for (int k = 0; k < HID; ++k) a = fmaf(xrow[k], lin_w[k * HID + j], a);
        lintab[c * HID + j] = a;
    }
}

// ---------------------------------------------------------------------------
// Pass 2: RELATION-SORTED scatter into padded per-node buckets.
// Final payload word: src(16) | combo(src)(9)<<18. cnt3 = c0|c1<<8|c2<<16.
__global__ __launch_bounds__(256) void build2_kernel(const int* __restrict__ bcnt,
                                                     const int* __restrict__ bucket,
                                                     const unsigned short* __restrict__ combo,
                                                     int* __restrict__ cnt3,
                                                     int* __restrict__ payload) {
    __shared__ int lcnt[256 * 3];
    for (int i = threadIdx.x; i < 768; i += 256) lcnt[i] = 0;
    __syncthreads();
    int b = blockIdx.x;
    int n0 = b << 8;
    int cb = min(bcnt[b], CAP1);
    const int* bk = bucket + b * CAP1;
    for (int i = threadIdx.x; i < cb; i += 256) {
        int v = bk[i];
        atomicAdd(&lcnt[((v >> 18) & 255) * 3 + ((v >> 16) & 3)], 1);
    }
    __syncthreads();
    int t = threadIdx.x;
    int c0 = min(lcnt[t * 3 + 0], CAP);
    int c1 = min(lcnt[t * 3 + 1], CAP - c0);
    int c2 = min(lcnt[t * 3 + 2], CAP - c0 - c1);
    __syncthreads();
    lcnt[t * 3 + 0] = 0;
    lcnt[t * 3 + 1] = c0;
    lcnt[t * 3 + 2] = c0 + c1;
    int node = n0 + t;
    if (node < N_NODES) cnt3[node] = c0 | (c1 << 8) | (c2 << 16);
    __syncthreads();
    for (int i = threadIdx.x; i < cb; i += 256) {
        int v = bk[i];
        int dl = (v >> 18) & 255;
        int r = (v >> 16) & 3;
        int sc = v & 0xffff;
        int pos = atomicAdd(&lcnt[dl * 3 + r], 1);
        if (pos < CAP)
            payload[((n0 + dl) << 6) + pos] = sc | ((int)combo[sc] << 18);
    }
}

// ---------------------------------------------------------------------------
// LAYER 1 fused: branch-free fp8 segment gather from ytab + lintab + LN.
// Emits xb (bf16, exact, for fused_layer's lin matmul) AND xf8 (fp8).
__global__ __launch_bounds__(256) void gather_ln1_kernel(
    const int* __restrict__ cnt3, const int* __restrict__ payload,
    const uint2* __restrict__ ytab8, const float* __restrict__ lintab,
    const unsigned short* __restrict__ combo, const float* __restrict__ lng,
    const float* __restrict__ lnb, uint4* __restrict__ xb4,
    uint2* __restrict__ xf8) {
    int tid = blockIdx.x * 256 + threadIdx.x;
    int node = tid >> 4;  // 3125 blocks exact
    int l16 = tid & 15;
    int c3 = cnt3[node];
    int c0 = c3 & 255, c1 = (c3 >> 8) & 255, c2 = (c3 >> 16) & 255;
    int tot = c0 + c1 + c2;
    float inv = 1.0f / (float)max(tot, 1);
    const int* pl = payload + (node << 6);
    float a[8] = {};
    int e = 0;
#pragma unroll 1
    for (int r = 0; r < 3; ++r) {
        int e1 = (r == 0) ? c0 : (r == 1) ? c0 + c1 : tot;
        int base = (r * NCOMBO) << 4;
        for (; e + 4 <= e1; e += 4) {
            int pA = pl[e], pB = pl[e + 1], pC = pl[e + 2], pD = pl[e + 3];
            uint2 vA = ytab8[base + ((pA >> 18) << 4) + l16];
            uint2 vB = ytab8[base + ((pB >> 18) << 4) + l16];
            uint2 vC = ytab8[base + ((pC >> 18) << 4) + l16];
            uint2 vD = ytab8[base + ((pD >> 18) << 4) + l16];
            acc8_fp8(a, vA);
            acc8_fp8(a, vB);
            acc8_fp8(a, vC);
            acc8_fp8(a, vD);
        }
        if (e + 2 <= e1) {
            int pA = pl[e], pB = pl[e + 1];
            uint2 vA = ytab8[base + ((pA >> 18) << 4) + l16];
            uint2 vB = ytab8[base + ((pB >> 18) << 4) + l16];
            acc8_fp8(a, vA);
            acc8_fp8(a, vB);
            e += 2;
        }
        if (e < e1) {
            int p = pl[e]; ++e;
            acc8_fp8(a, ytab8[base + ((p >> 18) << 4) + l16]);
        }
    }
    const float* lrow = lintab + (int)combo[node] * HID + l16 * 8;
    float v[8], s = 0.f, q = 0.f;
#pragma unroll
    for (int j = 0; j < 8; ++j) {
        v[j] = fmaf(a[j], inv, lrow[j]);
        s += v[j];
        q += v[j] * v[j];
    }
#pragma unroll
    for (int mk = 1; mk < 16; mk <<= 1) {
        s += __shfl_xor(s, mk);
        q += __shfl_xor(q, mk);
    }
    float mu = s * (1.0f / HID);
    float rstd = rsqrtf(q * (1.0f / HID) - mu * mu + LN_EPS);
    const float* g8 = lng + l16 * 8;
    const float* b8 = lnb + l16 * 8;
    float o[8];
#pragma unroll
    for (int j = 0; j < 8; ++j) o[j] = (v[j] - mu) * rstd * g8[j] + b8[j];
    uint4 w;
    w.x = packbf2(o[0], o[1]);
    w.y = packbf2(o[2], o[3]);
    w.z = packbf2(o[4], o[5]);
    w.w = packbf2(o[6], o[7]);
    xb4[(node << 4) + l16] = w;
    int lo = 0, hi = 0;
    lo = __builtin_amdgcn_cvt_pk_fp8_f32(o[0], o[1], lo, false);
    lo = __builtin_amdgcn_cvt_pk_fp8_f32(o[2], o[3], lo, true);
    hi = __builtin_amdgcn_cvt_pk_fp8_f32(o[4], o[5], hi, false);
    hi = __builtin_amdgcn_cvt_pk_fp8_f32(o[6], o[7], hi, true);
    xf8[(node << 4) + l16] = make_uint2((unsigned)lo, (unsigned)hi);
}

// ---------------------------------------------------------------------------
// LAYER 2 gather over fp8 rows (8B/lane): branch-free segments, fp32 accum,
// bf16 s_r stores. LDS-free, max occupancy (round-1 lesson).
__global__ __launch_bounds__(256) void gather3_kernel(const int* __restrict__ cnt3,
                                                      const int* __restrict__ payload,
                                                      const uint2* __restrict__ xf8,
                                                      uint4* __restrict__ s0,
                                                      uint4* __restrict__ s1,
                                                      uint4* __restrict__ s2) {
    int tid = blockIdx.x * 256 + threadIdx.x;
    int node = tid >> 4;
    int l16 = tid & 15;
    int c3 = cnt3[node];
    int c0 = c3 & 255, c1 = (c3 >> 8) & 255, c2 = (c3 >> 16) & 255;
    int tot = c0 + c1 + c2;
    float inv = 1.0f / (float)max(tot, 1);
    const int* pl = payload + (node << 6);
    int o = node * 16 + l16;
    int e = 0;
#pragma unroll 1
    for (int r = 0; r < 3; ++r) {
        int e1 = (r == 0) ? c0 : (r == 1) ? c0 + c1 : tot;
        float a[8] = {};
        for (; e + 4 <= e1; e += 4) {
            int pA = pl[e], pB = pl[e + 1], pC = pl[e + 2], pD = pl[e + 3];
            uint2 vA = xf8[((pA & 0xffff) << 4) + l16];
            uint2 vB = xf8[((pB & 0xffff) << 4) + l16];
            uint2 vC = xf8[((pC & 0xffff) << 4) + l16];
            uint2 vD = xf8[((pD & 0xffff) << 4) + l16];
            acc8_fp8(a, vA);
            acc8_fp8(a, vB);
            acc8_fp8(a, vC);
            acc8_fp8(a, vD);
        }
        if (e + 2 <= e1) {
            int pA = pl[e], pB = pl[e + 1];
            uint2 vA = xf8[((pA & 0xffff) << 4) + l16];
            uint2 vB = xf8[((pB & 0xffff) << 4) + l16];
            acc8_fp8(a, vA);
            acc8_fp8(a, vB);
            e += 2;
        }
        if (e < e1) {
            int p = pl[e]; ++e;
            acc8_fp8(a, xf8[((p & 0xffff) << 4) + l16]);
        }
        uint4 w;
        w.x = packbf2(a[0] * inv, a[1] * inv);
        w.y = packbf2(a[2] * inv, a[3] * inv);
        w.z = packbf2(a[4] * inv, a[5] * inv);
        w.w = packbf2(a[6] * inv, a[7] * inv);
        if (r == 0) s0[o] = w;
        else if (r == 1) s1[o] = w;
        else s2[o] = w;
    }
}

// ---------------------------------------------------------------------------
// Layer-2 fused GEMM+LN+pool, 32x32x16 MFMA, wave-private 32-node groups.
// R3: full A-prefetch (32 loads -> 128 VGPR, free: LDS pins 8 waves/CU) with
// the first group's loads hoisted ABOVE the Wt barrier (T14 issue-early),
// so A-gather latency hides under the 139 KB weight stage.
__global__ __launch_bounds__(512) void fused_layer_kernel(
    const unsigned short* __restrict__ s0, const unsigned short* __restrict__ s1,
    const unsigned short* __restrict__ s2, const unsigned short* __restrict__ xb,
    const uint4* __restrict__ wbuf, const float* __restrict__ lb,
    const float* __restrict__ lng, const float* __restrict__ lnb,
    float* __restrict__ pooled, const float* __restrict__ reg_w,
    const float* __restrict__ reg_b, float* __restrict__ out,
    int* __restrict__ done) {
    __shared__ __align__(16) unsigned short Wt[4 * HID * WT_STRIDE];  // 139264 B
    __shared__ float csh[3 * HID];
    __shared__ float pooled_sh[HID];
    __shared__ int lastFlag;

    int wave = threadIdx.x >> 6;
    int lane = threadIdx.x & 63;
    int n32 = lane & 31;
    int hf = lane >> 5;

    int g0 = wave * gridDim.x + blockIdx.x;
    size_t rofs0 = (size_t)(g0 * 32 + n32) * HID + hf * 8;
    bf16x8 areg[4][8];
    // issue-early: first group's 32 A-loads before the staging barrier
    if (g0 < NG32) {
        const unsigned short* a0 = s0 + rofs0;
        const unsigned short* a1 = s1 + rofs0;
        const unsigned short* a2 = s2 + rofs0;
        const unsigned short* a3 = xb + rofs0;
#pragma unroll
        for (int t = 0; t < 8; ++t) {
            areg[0][t] = *(const bf16x8*)(a0 + t * 16);
            areg[1][t] = *(const bf16x8*)(a1 + t * 16);
            areg[2][t] = *(const bf16x8*)(a2 + t * 16);
            areg[3][t] = *(const bf16x8*)(a3 + t * 16);
        }
    }

    if (threadIdx.x < HID) {
        pooled_sh[threadIdx.x] = 0.0f;
        csh[threadIdx.x] = lb[threadIdx.x];
        csh[HID + threadIdx.x] = lng[threadIdx.x];
        csh[2 * HID + threadIdx.x] = lnb[threadIdx.x];
    }
    uint4* wt4 = (uint4*)Wt;
#pragma unroll
    for (int i = 0; i < 17; ++i)
        wt4[i * 512 + threadIdx.x] = wbuf[i * 512 + threadIdx.x];
    __syncthreads();

    float pacc[4] = {0.f, 0.f, 0.f, 0.f};

#pragma unroll 1
    for (int g = g0; g < NG32; g += gridDim.x * 8) {
        if (g != g0) {  // rare second group: prefetch now
            size_t rofs = (size_t)(g * 32 + n32) * HID + hf * 8;
            const unsigned short* a0 = s0 + rofs;
            const unsigned short* a1 = s1 + rofs;
            const unsigned short* a2 = s2 + rofs;
            const unsigned short* a3 = xb + rofs;
#pragma unroll
            for (int t = 0; t < 8; ++t) {
                areg[0][t] = *(const bf16x8*)(a0 + t * 16);
                areg[1][t] = *(const bf16x8*)(a1 + t * 16);
                areg[2][t] = *(const bf16x8*)(a2 + t * 16);
                areg[3][t] = *(const bf16x8*)(a3 + t * 16);
            }
        }
        int node0 = g * 32;
        f32x16 acc[4];
#pragma unroll
        for (int ct = 0; ct < 4; ++ct)
#pragma unroll
            for (int i = 0; i < 16; ++i) acc[ct][i] = 0.0f;

#pragma unroll
        for (int mat = 0; mat < 4; ++mat) {
            const unsigned short* wm = Wt + mat * (HID * WT_STRIDE) + n32 * WT_STRIDE + hf * 8;
#pragma unroll
            for (int t = 0; t < 8; ++t) {
#pragma unroll
                for (int ct = 0; ct < 4; ++ct) {
                    bf16x8 bfr = *(const bf16x8*)(wm + ct * 32 * WT_STRIDE + t * 16);
                    acc[ct] = __builtin_amdgcn_mfma_f32_32x32x16_bf16(areg[mat][t], bfr, acc[ct], 0, 0, 0);
                }
            }
        }
#pragma unroll
        for (int reg = 0; reg < 16; ++reg) {
            int row = node0 + (reg & 3) + 8 * (reg >> 2) + 4 * hf;
            float v[4];
            float s = 0.f, q = 0.f;
#pragma unroll
            for (int ct = 0; ct < 4; ++ct) {
                v[ct] = acc[ct][reg] + csh[ct * 32 + n32];
                s += v[ct];
                q += v[ct] * v[ct];
            }
#pragma unroll
            for (int mk = 1; mk < 32; mk <<= 1) {
                s += __shfl_xor(s, mk);
                q += __shfl_xor(q, mk);
            }
            float mu = s * (1.0f / HID);
            float rstd = rsqrtf(q * (1.0f / HID) - mu * mu + LN_EPS);
            if (row < N_NODES) {
#pragma unroll
                for (int ct = 0; ct < 4; ++ct) {
                    int col = ct * 32 + n32;
                    pacc[ct] += (v[ct] - mu) * rstd * csh[HID + col] + csh[2 * HID + col];
                }
            }
        }
    }

#pragma unroll
    for (int ct = 0; ct < 4; ++ct) {
        float t = pacc[ct] + __shfl_xor(pacc[ct], 32);
        if (hf == 0) atomicAdd(&pooled_sh[ct * 32 + n32], t);
    }
    __syncthreads();
    if (threadIdx.x < HID) atomicAdd(&pooled[threadIdx.x], pooled_sh[threadIdx.x]);

    // ---- folded final reduction (last block) ----
    __threadfence();
    __syncthreads();
    if (threadIdx.x == 0)
        lastFlag = (atomicAdd(done, 1) == (int)gridDim.x - 1);
    __syncthreads();
    if (lastFlag && threadIdx.x < 64) {
        int l = threadIdx.x;
        // atomic fetch-add(0) reads take the same coherent path as the writes
        float s = atomicAdd(&pooled[l], 0.0f) * reg_w[l] +
                  atomicAdd(&pooled[64 + l], 0.0f) * reg_w[64 + l];
#pragma unroll
        for (int o = 32; o; o >>= 1) s += __shfl_down(s, o);
        if (l == 0) out[0] = s * (1.0f / N_NODES) + reg_b[0];
    }
}

// ---------------------------------------------------------------------------
extern "C" void kernel_launch(void* const* d_in, const int* in_sizes, int n_in,
                              void* d_out, int out_size, void* d_ws, size_t ws_size,
                              hipStream_t stream) {
    const int* z = (const int*)d_in[0];
    const int* nt = (const int*)d_in[1];
    const int* ei = (const int*)d_in[2];
    const int* et = (const int*)d_in[3];
    const float* z_embed = (const float*)d_in[4];
    const float* enc_w1 = (const float*)d_in[5];
    const float* enc_b1 = (const float*)d_in[6];
    const float* enc_w2 = (const float*)d_in[7];
    const float* enc_b2 = (const float*)d_in[8];
    const float* lin_w = (const float*)d_in[9];
    const float* lin_b = (const float*)d_in[10];
    const float* rel_w = (const float*)d_in[11];
    const float* ln_g = (const float*)d_in[12];
    const float* ln_b = (const float*)d_in[13];
    const float* reg_w = (const float*)d_in[14];
    const float* reg_b = (const float*)d_in[15];
    float* out = (float*)d_out;

    const size_t NHb = (size_t)NROWS * HID;
    char* p = (char*)d_ws;
    unsigned short* xb = (unsigned short*)p;    p += NHb * 2;
    unsigned short* s0 = (unsigned short*)p;    p += NHb * 2;
    unsigned short* s1 = (unsigned short*)p;    p += NHb * 2;
    unsigned short* s2 = (unsigned short*)p;    p += NHb * 2;
    uint2* xf8 = (uint2*)p;                     p += NHb;      // fp8 copy, 6.4 MB
    unsigned short* wbuf = (unsigned short*)p;  p += (size_t)4 * HID * WT_STRIDE * 2;
    unsigned int* ytab = (unsigned int*)p;      p += (size_t)N_REL * NCOMBO * HID;  // fp8
    float* lintab = (float*)p;                  p += NCOMBO * HID * 4;
    unsigned short* combo = (unsigned short*)p; p += N_NODES * 2;
    float* pooled = (float*)p;                  p += HID * 4;
    int* cnt3 = (int*)p;                        p += N_NODES * 4;
    int* bcnt = (int*)p;                        p += NBKT * 4;
    int* done = (int*)p;                        p += 4;        // adjacent to bcnt
    int* bucket = (int*)p;                      p += (size_t)NBKT * CAP1 * 4;
    int* payload = (int*)p;                     p += (size_t)N_NODES * CAP * 4;

    const int* src = ei;
    const int* dst = ei + N_EDGES;

    hipMemsetAsync(bcnt, 0, (NBKT + 1) * sizeof(int), stream);  // bcnt + done

    // front-end: edge binning || encoder tables || weight prep (one dispatch)
    build_tables_kernel<<<NBKT + NCOMBO + 256, 256, 0, stream>>>(
        src, dst, et, z, nt, z_embed, enc_w1, enc_b1, enc_w2, enc_b2,
        rel_w, lin_w, lin_b, combo, bcnt, bucket, ytab, lintab, wbuf, pooled);

    build2_kernel<<<NBKT, 256, 0, stream>>>(bcnt, bucket, combo, cnt3, payload);

    // layer 1: fused fp8 table-gather + lin + LN -> xb (bf16) + xf8 (fp8)
    gather_ln1_kernel<<<3125, 256, 0, stream>>>(cnt3, payload, (const uint2*)ytab, lintab,
                                                combo, ln_g, ln_b, (uint4*)xb, xf8);
    // layer 2: fp8 branch-free gather + MFMA fused layer (pool + final fold)
    gather3_kernel<<<3125, 256, 0, stream>>>(cnt3, payload, xf8,
                                             (uint4*)s0, (uint4*)s1, (uint4*)s2);
    fused_layer_kernel<<<256, 512, 0, stream>>>(
        s0, s1, s2, xb, (const uint4*)wbuf, lin_b + HID, ln_g + HID, ln_b + HID,
        pooled, reg_w, reg_b, out, done);
}

// Round 4
// 361.507 us; speedup vs baseline: 1.0041x; 1.0041x over previous
//
#include <hip/hip_runtime.h>

#define N_NODES 50000
#define N_EDGES 800000
#define FEAT 64
#define HID 128
#define N_TYPES 4
#define N_REL 3
#define N_LAYERS 2
#define LN_EPS 1e-5f
#define NROWS 50016   // 50000 padded to 32 (1563 groups of 32)
#define NG32 1563
#define CAP 64        // per-dst bucket capacity
#define NBKT 196      // coarse buckets: dst>>8
#define CAP1 4608     // coarse bucket capacity (mean 4082, +8 sigma)
#define EPB 4096      // edges per bin1 block
#define BINCAP 56     // per-block per-bin LDS capacity (mean 20.9, +7.7 sigma)
#define NCOMBO 400    // 100 z-values x 4 types
#define WT_STRIDE 136

typedef __attribute__((ext_vector_type(8))) short bf16x8;
typedef __attribute__((ext_vector_type(16))) float f32x16;
typedef __attribute__((ext_vector_type(2))) float f32x2;

static __device__ inline unsigned short f2bf(float f) {
    unsigned int u = __float_as_uint(f);
    return (unsigned short)((u + 0x7fffu + ((u >> 16) & 1u)) >> 16);
}
static __device__ inline unsigned int packbf2(float lo, float hi) {
    return (unsigned int)f2bf(lo) | ((unsigned int)f2bf(hi) << 16);
}

// decode 8 fp8-e4m3 (uint2) -> accumulate into a[0..7]
static __device__ inline void acc8_fp8(float* a, uint2 w) {
    f32x2 d0 = __builtin_amdgcn_cvt_pk_f32_fp8((int)w.x, false);
    f32x2 d1 = __builtin_amdgcn_cvt_pk_f32_fp8((int)w.x, true);
    f32x2 d2 = __builtin_amdgcn_cvt_pk_f32_fp8((int)w.y, false);
    f32x2 d3 = __builtin_amdgcn_cvt_pk_f32_fp8((int)w.y, true);
    a[0] += d0[0]; a[1] += d0[1]; a[2] += d1[0]; a[3] += d1[1];
    a[4] += d2[0]; a[5] += d2[1]; a[6] += d3[0]; a[7] += d3[1];
}

// ---------------------------------------------------------------------------
// MERGED front-end: blocks [0,196) = edge binning (+combo), [196,596) =
// encoder/layer-1 tables, [596,852) = layer-2 weight prep + pooled zero.
__global__ __launch_bounds__(256) void build_tables_kernel(
    const int* __restrict__ src, const int* __restrict__ dst,
    const int* __restrict__ et, const int* __restrict__ z,
    const int* __restrict__ nt,
    const float* __restrict__ z_embed, const float* __restrict__ w1,
    const float* __restrict__ b1, const float* __restrict__ w2,
    const float* __restrict__ b2, const float* __restrict__ rel_w,
    const float* __restrict__ lin_w, const float* __restrict__ lin_b,
    unsigned short* __restrict__ combo, int* __restrict__ bcnt,
    int* __restrict__ bucket, unsigned int* __restrict__ ytab,
    float* __restrict__ lintab, unsigned short* __restrict__ wbuf,
    float* __restrict__ pooled) {
    __shared__ int lbin[NBKT * BINCAP];  // 43.9 KB (bin1 branch only)
    __shared__ int lcnt[NBKT];
    __shared__ int lbase[NBKT];
    __shared__ float h[HID];             // encoder branch only
    __shared__ float xrow[HID];
    __shared__ float tmp[HID];

    int b = blockIdx.x;
    if (b < NBKT) {
        // ---- bin1: bin edges by dst>>8. Packed: src|et<<16|(dst&255)<<18 ----
        int ci = b * 256 + threadIdx.x;
        if (ci < N_NODES) combo[ci] = (unsigned short)(z[ci] * 4 + nt[ci]);
        for (int i = threadIdx.x; i < NBKT; i += 256) lcnt[i] = 0;
        __syncthreads();
        int base = b * EPB;
#pragma unroll
        for (int i = 0; i < EPB / 256; ++i) {
            int e = base + i * 256 + threadIdx.x;
            if (e < N_EDGES) {
                int d = dst[e];
                int bk = d >> 8;
                int v = src[e] | (et[e] << 16) | ((d & 255) << 18);
                int pos = atomicAdd(&lcnt[bk], 1);
                if (pos < BINCAP) lbin[bk * BINCAP + pos] = v;
            }
        }
        __syncthreads();
        if (threadIdx.x < NBKT) {
            int c = min(lcnt[threadIdx.x], BINCAP);
            lcnt[threadIdx.x] = c;
            lbase[threadIdx.x] = atomicAdd(&bcnt[threadIdx.x], c);
        }
        __syncthreads();
        int wv = threadIdx.x >> 6, ln = threadIdx.x & 63;
        for (int bb = wv; bb < NBKT; bb += 4) {
            int c = lcnt[bb];
            if (ln < c) {
                int gp = lbase[bb] + ln;
                if (gp < CAP1) bucket[bb * CAP1 + gp] = lbin[bb * BINCAP + ln];
            }
        }
        return;
    }
    if (b >= NBKT + NCOMBO) {
        // ---- weight prep for layer 2: 256 blocks x 256 threads = 65536 ----
        int pb = b - (NBKT + NCOMBO);
        if (pb == 0 && threadIdx.x < HID) pooled[threadIdx.x] = 0.0f;
        int idx = pb * 256 + threadIdx.x;
        int k = idx & 127;
        int col = (idx >> 7) & 127;
        int mat = idx >> 14;
        float w = (mat < 3) ? rel_w[(((size_t)(3 + mat)) * HID + k) * HID + col]
                            : lin_w[((size_t)(HID + k)) * HID + col];
        wbuf[(size_t)mat * HID * WT_STRIDE + col * WT_STRIDE + k] = f2bf(w);
        return;
    }
    // ---- encoder + layer-1 tables (one combo per block; threads<128 act) ----
    int c = b - NBKT;  // 0..399
    int zi = c >> 2;
    int t = c & 3;
    int j = threadIdx.x;
    bool act = j < HID;
    if (act) {
        float acc = b1[t * HID + j];
#pragma unroll 8
        for (int k = 0; k < FEAT; ++k)
            acc = fmaf(z_embed[zi * FEAT + k], w1[((size_t)t * FEAT + k) * HID + j], acc);
        h[j] = fmaxf(acc, 0.0f);
    }
    __syncthreads();
    if (act) {
        float acc2 = b2[t * HID + j];
#pragma unroll 8
        for (int k = 0; k < HID; ++k)
            acc2 = fmaf(h[k], w2[(size_t)t * HID * HID + k * HID + j], acc2);
        xrow[j] = acc2;
    }
    __syncthreads();
#pragma unroll 1
    for (int r = 0; r < N_REL; ++r) {
        if (act) {
            float a = 0.f;
            const float* W = rel_w + (size_t)r * HID * HID;  // layer 0
#pragma unroll 8
            for (int k = 0; k < HID; ++k) a = fmaf(xrow[k], W[k * HID + j], a);
            tmp[j] = a;
        }
        __syncthreads();
        if (j < 32) {  // pack 4 fp8 per uint
            int w0 = __builtin_amdgcn_cvt_pk_fp8_f32(tmp[4 * j], tmp[4 * j + 1], 0, false);
            w0 = __builtin_amdgcn_cvt_pk_fp8_f32(tmp[4 * j + 2], tmp[4 * j + 3], w0, true);
            ytab[(r * NCOMBO + c) * 32 + j] = (unsigned)w0;
        }
        __syncthreads();
    }
    if (act) {
        float a = lin_b[j];
#pragma unroll 8
        for (int k = 0; k < HID; ++k) a = fmaf(xrow[k], lin_w[k * HID + j], a);
        lintab[c * HID + j] = a;
    }
}

// ---------------------------------------------------------------------------
// Pass 2: RELATION-SORTED scatter into padded per-node buckets.
// Final payload word: src(16) | combo(src)(9)<<18. cnt3 = c0|c1<<8|c2<<16.
__global__ __launch_bounds__(256) void build2_kernel(const int* __restrict__ bcnt,
                                                     const int* __restrict__ bucket,
                                                     const unsigned short* __restrict__ combo,
                                                     int* __restrict__ cnt3,
                                                     int* __restrict__ payload) {
    __shared__ int lcnt[256 * 3];
    for (int i = threadIdx.x; i < 768; i += 256) lcnt[i] = 0;
    __syncthreads();
    int b = blockIdx.x;
    int n0 = b << 8;
    int cb = min(bcnt[b], CAP1);
    const int* bk = bucket + b * CAP1;
    for (int i = threadIdx.x; i < cb; i += 256) {
        int v = bk[i];
        atomicAdd(&lcnt[((v >> 18) & 255) * 3 + ((v >> 16) & 3)], 1);
    }
    __syncthreads();
    int t = threadIdx.x;
    int c0 = min(lcnt[t * 3 + 0], CAP);
    int c1 = min(lcnt[t * 3 + 1], CAP - c0);
    int c2 = min(lcnt[t * 3 + 2], CAP - c0 - c1);
    __syncthreads();
    lcnt[t * 3 + 0] = 0;
    lcnt[t * 3 + 1] = c0;
    lcnt[t * 3 + 2] = c0 + c1;
    int node = n0 + t;
    if (node < N_NODES) cnt3[node] = c0 | (c1 << 8) | (c2 << 16);
    __syncthreads();
    for (int i = threadIdx.x; i < cb; i += 256) {
        int v = bk[i];
        int dl = (v >> 18) & 255;
        int r = (v >> 16) & 3;
        int sc = v & 0xffff;
        int pos = atomicAdd(&lcnt[dl * 3 + r], 1);
        if (pos < CAP)
            payload[((n0 + dl) << 6) + pos] = sc | ((int)combo[sc] << 18);
    }
}

// ---------------------------------------------------------------------------
// LAYER 1 fused: branch-free fp8 segment gather from ytab + lintab + LN.
// Emits xb (bf16, exact, for fused_layer's lin matmul) AND xf8 (fp8).
__global__ __launch_bounds__(256) void gather_ln1_kernel(
    const int* __restrict__ cnt3, const int* __restrict__ payload,
    const uint2* __restrict__ ytab8, const float* __restrict__ lintab,
    const unsigned short* __restrict__ combo, const float* __restrict__ lng,
    const float* __restrict__ lnb, uint4* __restrict__ xb4,
    uint2* __restrict__ xf8) {
    int tid = blockIdx.x * 256 + threadIdx.x;
    int node = tid >> 4;  // 3125 blocks exact
    int l16 = tid & 15;
    int c3 = cnt3[node];
    int c0 = c3 & 255, c1 = (c3 >> 8) & 255, c2 = (c3 >> 16) & 255;
    int tot = c0 + c1 + c2;
    float inv = 1.0f / (float)max(tot, 1);
    const int* pl = payload + (node << 6);
    float a[8] = {};
    int e = 0;
#pragma unroll 1
    for (int r = 0; r < 3; ++r) {
        int e1 = (r == 0) ? c0 : (r == 1) ? c0 + c1 : tot;
        int base = (r * NCOMBO) << 4;
        for (; e + 4 <= e1; e += 4) {
            int pA = pl[e], pB = pl[e + 1], pC = pl[e + 2], pD = pl[e + 3];
            uint2 vA = ytab8[base + ((pA >> 18) << 4) + l16];
            uint2 vB = ytab8[base + ((pB >> 18) << 4) + l16];
            uint2 vC = ytab8[base + ((pC >> 18) << 4) + l16];
            uint2 vD = ytab8[base + ((pD >> 18) << 4) + l16];
            acc8_fp8(a, vA);
            acc8_fp8(a, vB);
            acc8_fp8(a, vC);
            acc8_fp8(a, vD);
        }
        if (e + 2 <= e1) {
            int pA = pl[e], pB = pl[e + 1];
            uint2 vA = ytab8[base + ((pA >> 18) << 4) + l16];
            uint2 vB = ytab8[base + ((pB >> 18) << 4) + l16];
            acc8_fp8(a, vA);
            acc8_fp8(a, vB);
            e += 2;
        }
        if (e < e1) {
            int p = pl[e]; ++e;
            acc8_fp8(a, ytab8[base + ((p >> 18) << 4) + l16]);
        }
    }
    const float* lrow = lintab + (int)combo[node] * HID + l16 * 8;
    float v[8], s = 0.f, q = 0.f;
#pragma unroll
    for (int j = 0; j < 8; ++j) {
        v[j] = fmaf(a[j], inv, lrow[j]);
        s += v[j];
        q += v[j] * v[j];
    }
#pragma unroll
    for (int mk = 1; mk < 16; mk <<= 1) {
        s += __shfl_xor(s, mk);
        q += __shfl_xor(q, mk);
    }
    float mu = s * (1.0f / HID);
    float rstd = rsqrtf(q * (1.0f / HID) - mu * mu + LN_EPS);
    const float* g8 = lng + l16 * 8;
    const float* b8 = lnb + l16 * 8;
    float o[8];
#pragma unroll
    for (int j = 0; j < 8; ++j) o[j] = (v[j] - mu) * rstd * g8[j] + b8[j];
    uint4 w;
    w.x = packbf2(o[0], o[1]);
    w.y = packbf2(o[2], o[3]);
    w.z = packbf2(o[4], o[5]);
    w.w = packbf2(o[6], o[7]);
    xb4[(node << 4) + l16] = w;
    int lo = 0, hi = 0;
    lo = __builtin_amdgcn_cvt_pk_fp8_f32(o[0], o[1], lo, false);
    lo = __builtin_amdgcn_cvt_pk_fp8_f32(o[2], o[3], lo, true);
    hi = __builtin_amdgcn_cvt_pk_fp8_f32(o[4], o[5], hi, false);
    hi = __builtin_amdgcn_cvt_pk_fp8_f32(o[6], o[7], hi, true);
    xf8[(node << 4) + l16] = make_uint2((unsigned)lo, (unsigned)hi);
}

// ---------------------------------------------------------------------------
// LAYER 2 gather over fp8 rows (8B/lane): branch-free segments, fp32 accum,
// bf16 s_r stores. LDS-free, max occupancy (round-1 lesson).
__global__ __launch_bounds__(256) void gather3_kernel(const int* __restrict__ cnt3,
                                                      const int* __restrict__ payload,
                                                      const uint2* __restrict__ xf8,
                                                      uint4* __restrict__ s0,
                                                      uint4* __restrict__ s1,
                                                      uint4* __restrict__ s2) {
    int tid = blockIdx.x * 256 + threadIdx.x;
    int node = tid >> 4;
    int l16 = tid & 15;
    int c3 = cnt3[node];
    int c0 = c3 & 255, c1 = (c3 >> 8) & 255, c2 = (c3 >> 16) & 255;
    int tot = c0 + c1 + c2;
    float inv = 1.0f / (float)max(tot, 1);
    const int* pl = payload + (node << 6);
    int o = node * 16 + l16;
    int e = 0;
#pragma unroll 1
    for (int r = 0; r < 3; ++r) {
        int e1 = (r == 0) ? c0 : (r == 1) ? c0 + c1 : tot;
        float a[8] = {};
        for (; e + 4 <= e1; e += 4) {
            int pA = pl[e], pB = pl[e + 1], pC = pl[e + 2], pD = pl[e + 3];
            uint2 vA = xf8[((pA & 0xffff) << 4) + l16];
            uint2 vB = xf8[((pB & 0xffff) << 4) + l16];
            uint2 vC = xf8[((pC & 0xffff) << 4) + l16];
            uint2 vD = xf8[((pD & 0xffff) << 4) + l16];
            acc8_fp8(a, vA);
            acc8_fp8(a, vB);
            acc8_fp8(a, vC);
            acc8_fp8(a, vD);
        }
        if (e + 2 <= e1) {
            int pA = pl[e], pB = pl[e + 1];
            uint2 vA = xf8[((pA & 0xffff) << 4) + l16];
            uint2 vB = xf8[((pB & 0xffff) << 4) + l16];
            acc8_fp8(a, vA);
            acc8_fp8(a, vB);
            e += 2;
        }
        if (e < e1) {
            int p = pl[e]; ++e;
            acc8_fp8(a, xf8[((p & 0xffff) << 4) + l16]);
        }
        uint4 w;
        w.x = packbf2(a[0] * inv, a[1] * inv);
        w.y = packbf2(a[2] * inv, a[3] * inv);
        w.z = packbf2(a[4] * inv, a[5] * inv);
        w.w = packbf2(a[6] * inv, a[7] * inv);
        if (r == 0) s0[o] = w;
        else if (r == 1) s1[o] = w;
        else s2[o] = w;
    }
}

// ---------------------------------------------------------------------------
// Layer-2 fused GEMM+LN+pool, 32x32x16 MFMA, wave-private 32-node groups.
// R4: full A-prefetch kept, but __launch_bounds__(512, 2) raises the VGPR
// cap to 256 (2 waves/SIMD — the LDS-pinned occupancy anyway). R3's version
// defaulted to a 128-VGPR cap and spilled areg to scratch (WRITE_SIZE
// 136 KB -> 193 MB). areg(128) + acc(64) + ~30 addressing fits 256.
__global__ __launch_bounds__(512, 2) void fused_layer_kernel(
    const unsigned short* __restrict__ s0, const unsigned short* __restrict__ s1,
    const unsigned short* __restrict__ s2, const unsigned short* __restrict__ xb,
    const uint4* __restrict__ wbuf, const float* __restrict__ lb,
    const float* __restrict__ lng, const float* __restrict__ lnb,
    float* __restrict__ pooled, const float* __restrict__ reg_w,
    const float* __restrict__ reg_b, float* __restrict__ out,
    int* __restrict__ done) {
    __shared__ __align__(16) unsigned short Wt[4 * HID * WT_STRIDE];  // 139264 B
    __shared__ float csh[3 * HID];
    __shared__ float pooled_sh[HID];
    __shared__ int lastFlag;

    int wave = threadIdx.x >> 6;
    int lane = threadIdx.x & 63;
    int n32 = lane & 31;
    int hf = lane >> 5;

    int g0 = wave * gridDim.x + blockIdx.x;
    size_t rofs0 = (size_t)(g0 * 32 + n32) * HID + hf * 8;
    bf16x8 areg[4][8];
    // issue-early: first group's 32 A-loads before the staging barrier
    if (g0 < NG32) {
        const unsigned short* a0 = s0 + rofs0;
        const unsigned short* a1 = s1 + rofs0;
        const unsigned short* a2 = s2 + rofs0;
        const unsigned short* a3 = xb + rofs0;
#pragma unroll
        for (int t = 0; t < 8; ++t) {
            areg[0][t] = *(const bf16x8*)(a0 + t * 16);
            areg[1][t] = *(const bf16x8*)(a1 + t * 16);
            areg[2][t] = *(const bf16x8*)(a2 + t * 16);
            areg[3][t] = *(const bf16x8*)(a3 + t * 16);
        }
    }

    if (threadIdx.x < HID) {
        pooled_sh[threadIdx.x] = 0.0f;
        csh[threadIdx.x] = lb[threadIdx.x];
        csh[HID + threadIdx.x] = lng[threadIdx.x];
        csh[2 * HID + threadIdx.x] = lnb[threadIdx.x];
    }
    uint4* wt4 = (uint4*)Wt;
#pragma unroll
    for (int i = 0; i < 17; ++i)
        wt4[i * 512 + threadIdx.x] = wbuf[i * 512 + threadIdx.x];
    __syncthreads();

    float pacc[4] = {0.f, 0.f, 0.f, 0.f};

#pragma unroll 1
    for (int g = g0; g < NG32; g += gridDim.x * 8) {
        if (g != g0) {  // rare second group: prefetch now
            size_t rofs = (size_t)(g * 32 + n32) * HID + hf * 8;
            const unsigned short* a0 = s0 + rofs;
            const unsigned short* a1 = s1 + rofs;
            const unsigned short* a2 = s2 + rofs;
            const unsigned short* a3 = xb + rofs;
#pragma unroll
            for (int t = 0; t < 8; ++t) {
                areg[0][t] = *(const bf16x8*)(a0 + t * 16);
                areg[1][t] = *(const bf16x8*)(a1 + t * 16);
                areg[2][t] = *(const bf16x8*)(a2 + t * 16);
                areg[3][t] = *(const bf16x8*)(a3 + t * 16);
            }
        }
        int node0 = g * 32;
        f32x16 acc[4];
#pragma unroll
        for (int ct = 0; ct < 4; ++ct)
#pragma unroll
            for (int i = 0; i < 16; ++i) acc[ct][i] = 0.0f;

#pragma unroll
        for (int mat = 0; mat < 4; ++mat) {
            const unsigned short* wm = Wt + mat * (HID * WT_STRIDE) + n32 * WT_STRIDE + hf * 8;
#pragma unroll
            for (int t = 0; t < 8; ++t) {
#pragma unroll
                for (int ct = 0; ct < 4; ++ct) {
                    bf16x8 bfr = *(const bf16x8*)(wm + ct * 32 * WT_STRIDE + t * 16);
                    acc[ct] = __builtin_amdgcn_mfma_f32_32x32x16_bf16(areg[mat][t], bfr, acc[ct], 0, 0, 0);
                }
            }
        }
#pragma unroll
        for (int reg = 0; reg < 16; ++reg) {
            int row = node0 + (reg & 3) + 8 * (reg >> 2) + 4 * hf;
            float v[4];
            float s = 0.f, q = 0.f;
#pragma unroll
            for (int ct = 0; ct < 4; ++ct) {
                v[ct] = acc[ct][reg] + csh[ct * 32 + n32];
                s += v[ct];
                q += v[ct] * v[ct];
            }
#pragma unroll
            for (int mk = 1; mk < 32; mk <<= 1) {
                s += __shfl_xor(s, mk);
                q += __shfl_xor(q, mk);
            }
            float mu = s * (1.0f / HID);
            float rstd = rsqrtf(q * (1.0f / HID) - mu * mu + LN_EPS);
            if (row < N_NODES) {
#pragma unroll
                for (int ct = 0; ct < 4; ++ct) {
                    int col = ct * 32 + n32;
                    pacc[ct] += (v[ct] - mu) * rstd * csh[HID + col] + csh[2 * HID + col];
                }
            }
        }
    }

#pragma unroll
    for (int ct = 0; ct < 4; ++ct) {
        float t = pacc[ct] + __shfl_xor(pacc[ct], 32);
        if (hf == 0) atomicAdd(&pooled_sh[ct * 32 + n32], t);
    }
    __syncthreads();
    if (threadIdx.x < HID) atomicAdd(&pooled[threadIdx.x], pooled_sh[threadIdx.x]);

    // ---- folded final reduction (last block) ----
    __threadfence();
    __syncthreads();
    if (threadIdx.x == 0)
        lastFlag = (atomicAdd(done, 1) == (int)gridDim.x - 1);
    __syncthreads();
    if (lastFlag && threadIdx.x < 64) {
        int l = threadIdx.x;
        // atomic fetch-add(0) reads take the same coherent path as the writes
        float s = atomicAdd(&pooled[l], 0.0f) * reg_w[l] +
                  atomicAdd(&pooled[64 + l], 0.0f) * reg_w[64 + l];
#pragma unroll
        for (int o = 32; o; o >>= 1) s += __shfl_down(s, o);
        if (l == 0) out[0] = s * (1.0f / N_NODES) + reg_b[0];
    }
}

// ---------------------------------------------------------------------------
extern "C" void kernel_launch(void* const* d_in, const int* in_sizes, int n_in,
                              void* d_out, int out_size, void* d_ws, size_t ws_size,
                              hipStream_t stream) {
    const int* z = (const int*)d_in[0];
    const int* nt = (const int*)d_in[1];
    const int* ei = (const int*)d_in[2];
    const int* et = (const int*)d_in[3];
    const float* z_embed = (const float*)d_in[4];
    const float* enc_w1 = (const float*)d_in[5];
    const float* enc_b1 = (const float*)d_in[6];
    const float* enc_w2 = (const float*)d_in[7];
    const float* enc_b2 = (const float*)d_in[8];
    const float* lin_w = (const float*)d_in[9];
    const float* lin_b = (const float*)d_in[10];
    const float* rel_w = (const float*)d_in[11];
    const float* ln_g = (const float*)d_in[12];
    const float* ln_b = (const float*)d_in[13];
    const float* reg_w = (const float*)d_in[14];
    const float* reg_b = (const float*)d_in[15];
    float* out = (float*)d_out;

    const size_t NHb = (size_t)NROWS * HID;
    char* p = (char*)d_ws;
    unsigned short* xb = (unsigned short*)p;    p += NHb * 2;
    unsigned short* s0 = (unsigned short*)p;    p += NHb * 2;
    unsigned short* s1 = (unsigned short*)p;    p += NHb * 2;
    unsigned short* s2 = (unsigned short*)p;    p += NHb * 2;
    uint2* xf8 = (uint2*)p;                     p += NHb;      // fp8 copy, 6.4 MB
    unsigned short* wbuf = (unsigned short*)p;  p += (size_t)4 * HID * WT_STRIDE * 2;
    unsigned int* ytab = (unsigned int*)p;      p += (size_t)N_REL * NCOMBO * HID;  // fp8
    float* lintab = (float*)p;                  p += NCOMBO * HID * 4;
    unsigned short* combo = (unsigned short*)p; p += N_NODES * 2;
    float* pooled = (float*)p;                  p += HID * 4;
    int* cnt3 = (int*)p;                        p += N_NODES * 4;
    int* bcnt = (int*)p;                        p += NBKT * 4;
    int* done = (int*)p;                        p += 4;        // adjacent to bcnt
    int* bucket = (int*)p;                      p += (size_t)NBKT * CAP1 * 4;
    int* payload = (int*)p;                     p += (size_t)N_NODES * CAP * 4;

    const int* src = ei;
    const int* dst = ei + N_EDGES;

    hipMemsetAsync(bcnt, 0, (NBKT + 1) * sizeof(int), stream);  // bcnt + done

    // front-end: edge binning || encoder tables || weight prep (one dispatch)
    build_tables_kernel<<<NBKT + NCOMBO + 256, 256, 0, stream>>>(
        src, dst, et, z, nt, z_embed, enc_w1, enc_b1, enc_w2, enc_b2,
        rel_w, lin_w, lin_b, combo, bcnt, bucket, ytab, lintab, wbuf, pooled);

    build2_kernel<<<NBKT, 256, 0, stream>>>(bcnt, bucket, combo, cnt3, payload);

    // layer 1: fused fp8 table-gather + lin + LN -> xb (bf16) + xf8 (fp8)
    gather_ln1_kernel<<<3125, 256, 0, stream>>>(cnt3, payload, (const uint2*)ytab, lintab,
                                                combo, ln_g, ln_b, (uint4*)xb, xf8);
    // layer 2: fp8 branch-free gather + MFMA fused layer (pool + final fold)
    gather3_kernel<<<3125, 256, 0, stream>>>(cnt3, payload, xf8,
                                             (uint4*)s0, (uint4*)s1, (uint4*)s2);
    fused_layer_kernel<<<256, 512, 0, stream>>>(
        s0, s1, s2, xb, (const uint4*)wbuf, lin_b + HID, ln_g + HID, ln_b + HID,
        pooled, reg_w, reg_b, out, done);
}

// Round 5
// 232.707 us; speedup vs baseline: 1.5598x; 1.5535x over previous
//
#include <hip/hip_runtime.h>

#define N_NODES 50000
#define N_EDGES 800000
#define FEAT 64
#define HID 128
#define N_TYPES 4
#define N_REL 3
#define N_LAYERS 2
#define LN_EPS 1e-5f
#define NROWS 50016   // 50000 padded to 32 (1563 groups of 32)
#define NG32 1563
#define CAP 64        // per-dst bucket capacity
#define NBKT 196      // coarse buckets: dst>>8
#define CAP1 4608     // coarse bucket capacity (mean 4082, +8 sigma)
#define EPB 4096      // edges per bin1 block
#define BINCAP 56     // per-block per-bin LDS capacity (mean 20.9, +7.7 sigma)
#define NCOMBO 400    // 100 z-values x 4 types
#define WT_STRIDE 136

typedef __attribute__((ext_vector_type(8))) short bf16x8;
typedef __attribute__((ext_vector_type(16))) float f32x16;
typedef __attribute__((ext_vector_type(2))) float f32x2;

static __device__ inline unsigned short f2bf(float f) {
    unsigned int u = __float_as_uint(f);
    return (unsigned short)((u + 0x7fffu + ((u >> 16) & 1u)) >> 16);
}
static __device__ inline unsigned int packbf2(float lo, float hi) {
    return (unsigned int)f2bf(lo) | ((unsigned int)f2bf(hi) << 16);
}

// decode 8 fp8-e4m3 (uint2) -> accumulate into a[0..7]
static __device__ inline void acc8_fp8(float* a, uint2 w) {
    f32x2 d0 = __builtin_amdgcn_cvt_pk_f32_fp8((int)w.x, false);
    f32x2 d1 = __builtin_amdgcn_cvt_pk_f32_fp8((int)w.x, true);
    f32x2 d2 = __builtin_amdgcn_cvt_pk_f32_fp8((int)w.y, false);
    f32x2 d3 = __builtin_amdgcn_cvt_pk_f32_fp8((int)w.y, true);
    a[0] += d0[0]; a[1] += d0[1]; a[2] += d1[0]; a[3] += d1[1];
    a[4] += d2[0]; a[5] += d2[1]; a[6] += d3[0]; a[7] += d3[1];
}

// ---------------------------------------------------------------------------
// MERGED front-end: blocks [0,196) = edge binning (+combo), [196,596) =
// encoder/layer-1 tables, [596,852) = layer-2 weight prep + pooled zero.
__global__ __launch_bounds__(256) void build_tables_kernel(
    const int* __restrict__ src, const int* __restrict__ dst,
    const int* __restrict__ et, const int* __restrict__ z,
    const int* __restrict__ nt,
    const float* __restrict__ z_embed, const float* __restrict__ w1,
    const float* __restrict__ b1, const float* __restrict__ w2,
    const float* __restrict__ b2, const float* __restrict__ rel_w,
    const float* __restrict__ lin_w, const float* __restrict__ lin_b,
    unsigned short* __restrict__ combo, int* __restrict__ bcnt,
    int* __restrict__ bucket, unsigned int* __restrict__ ytab,
    float* __restrict__ lintab, unsigned short* __restrict__ wbuf,
    float* __restrict__ pooled) {
    __shared__ int lbin[NBKT * BINCAP];  // 43.9 KB (bin1 branch only)
    __shared__ int lcnt[NBKT];
    __shared__ int lbase[NBKT];
    __shared__ float h[HID];             // encoder branch only
    __shared__ float xrow[HID];
    __shared__ float tmp[HID];

    int b = blockIdx.x;
    if (b < NBKT) {
        // ---- bin1: bin edges by dst>>8. Packed: src|et<<16|(dst&255)<<18 ----
        int ci = b * 256 + threadIdx.x;
        if (ci < N_NODES) combo[ci] = (unsigned short)(z[ci] * 4 + nt[ci]);
        for (int i = threadIdx.x; i < NBKT; i += 256) lcnt[i] = 0;
        __syncthreads();
        int base = b * EPB;
#pragma unroll
        for (int i = 0; i < EPB / 256; ++i) {
            int e = base + i * 256 + threadIdx.x;
            if (e < N_EDGES) {
                int d = dst[e];
                int bk = d >> 8;
                int v = src[e] | (et[e] << 16) | ((d & 255) << 18);
                int pos = atomicAdd(&lcnt[bk], 1);
                if (pos < BINCAP) lbin[bk * BINCAP + pos] = v;
            }
        }
        __syncthreads();
        if (threadIdx.x < NBKT) {
            int c = min(lcnt[threadIdx.x], BINCAP);
            lcnt[threadIdx.x] = c;
            lbase[threadIdx.x] = atomicAdd(&bcnt[threadIdx.x], c);
        }
        __syncthreads();
        int wv = threadIdx.x >> 6, ln = threadIdx.x & 63;
        for (int bb = wv; bb < NBKT; bb += 4) {
            int c = lcnt[bb];
            if (ln < c) {
                int gp = lbase[bb] + ln;
                if (gp < CAP1) bucket[bb * CAP1 + gp] = lbin[bb * BINCAP + ln];
            }
        }
        return;
    }
    if (b >= NBKT + NCOMBO) {
        // ---- weight prep for layer 2: 256 blocks x 256 threads = 65536 ----
        int pb = b - (NBKT + NCOMBO);
        if (pb == 0 && threadIdx.x < HID) pooled[threadIdx.x] = 0.0f;
        int idx = pb * 256 + threadIdx.x;
        int k = idx & 127;
        int col = (idx >> 7) & 127;
        int mat = idx >> 14;
        float w = (mat < 3) ? rel_w[(((size_t)(3 + mat)) * HID + k) * HID + col]
                            : lin_w[((size_t)(HID + k)) * HID + col];
        wbuf[(size_t)mat * HID * WT_STRIDE + col * WT_STRIDE + k] = f2bf(w);
        return;
    }
    // ---- encoder + layer-1 tables (one combo per block; threads<128 act) ----
    int c = b - NBKT;  // 0..399
    int zi = c >> 2;
    int t = c & 3;
    int j = threadIdx.x;
    bool act = j < HID;
    if (act) {
        float acc = b1[t * HID + j];
#pragma unroll 8
        for (int k = 0; k < FEAT; ++k)
            acc = fmaf(z_embed[zi * FEAT + k], w1[((size_t)t * FEAT + k) * HID + j], acc);
        h[j] = fmaxf(acc, 0.0f);
    }
    __syncthreads();
    if (act) {
        float acc2 = b2[t * HID + j];
#pragma unroll 8
        for (int k = 0; k < HID; ++k)
            acc2 = fmaf(h[k], w2[(size_t)t * HID * HID + k * HID + j], acc2);
        xrow[j] = acc2;
    }
    __syncthreads();
#pragma unroll 1
    for (int r = 0; r < N_REL; ++r) {
        if (act) {
            float a = 0.f;
            const float* W = rel_w + (size_t)r * HID * HID;  // layer 0
#pragma unroll 8
            for (int k = 0; k < HID; ++k) a = fmaf(xrow[k], W[k * HID + j], a);
            tmp[j] = a;
        }
        __syncthreads();
        if (j < 32) {  // pack 4 fp8 per uint
            int w0 = __builtin_amdgcn_cvt_pk_fp8_f32(tmp[4 * j], tmp[4 * j + 1], 0, false);
            w0 = __builtin_amdgcn_cvt_pk_fp8_f32(tmp[4 * j + 2], tmp[4 * j + 3], w0, true);
            ytab[(r * NCOMBO + c) * 32 + j] = (unsigned)w0;
        }
        __syncthreads();
    }
    if (act) {
        float a = lin_b[j];
#pragma unroll 8
        for (int k = 0; k < HID; ++k) a = fmaf(xrow[k], lin_w[k * HID + j], a);
        lintab[c * HID + j] = a;
    }
}

// ---------------------------------------------------------------------------
// Pass 2: RELATION-SORTED scatter into padded per-node buckets.
// Final payload word: src(16) | combo(src)(9)<<18. cnt3 = c0|c1<<8|c2<<16.
__global__ __launch_bounds__(256) void build2_kernel(const int* __restrict__ bcnt,
                                                     const int* __restrict__ bucket,
                                                     const unsigned short* __restrict__ combo,
                                                     int* __restrict__ cnt3,
                                                     int* __restrict__ payload) {
    __shared__ int lcnt[256 * 3];
    for (int i = threadIdx.x; i < 768; i += 256) lcnt[i] = 0;
    __syncthreads();
    int b = blockIdx.x;
    int n0 = b << 8;
    int cb = min(bcnt[b], CAP1);
    const int* bk = bucket + b * CAP1;
    for (int i = threadIdx.x; i < cb; i += 256) {
        int v = bk[i];
        atomicAdd(&lcnt[((v >> 18) & 255) * 3 + ((v >> 16) & 3)], 1);
    }
    __syncthreads();
    int t = threadIdx.x;
    int c0 = min(lcnt[t * 3 + 0], CAP);
    int c1 = min(lcnt[t * 3 + 1], CAP - c0);
    int c2 = min(lcnt[t * 3 + 2], CAP - c0 - c1);
    __syncthreads();
    lcnt[t * 3 + 0] = 0;
    lcnt[t * 3 + 1] = c0;
    lcnt[t * 3 + 2] = c0 + c1;
    int node = n0 + t;
    if (node < N_NODES) cnt3[node] = c0 | (c1 << 8) | (c2 << 16);
    __syncthreads();
    for (int i = threadIdx.x; i < cb; i += 256) {
        int v = bk[i];
        int dl = (v >> 18) & 255;
        int r = (v >> 16) & 3;
        int sc = v & 0xffff;
        int pos = atomicAdd(&lcnt[dl * 3 + r], 1);
        if (pos < CAP)
            payload[((n0 + dl) << 6) + pos] = sc | ((int)combo[sc] << 18);
    }
}

// ---------------------------------------------------------------------------
// LAYER 1 fused: branch-free fp8 segment gather from ytab + lintab + LN.
// Emits xb (bf16, exact, for fused_layer's lin matmul) AND xf8 (fp8).
__global__ __launch_bounds__(256) void gather_ln1_kernel(
    const int* __restrict__ cnt3, const int* __restrict__ payload,
    const uint2* __restrict__ ytab8, const float* __restrict__ lintab,
    const unsigned short* __restrict__ combo, const float* __restrict__ lng,
    const float* __restrict__ lnb, uint4* __restrict__ xb4,
    uint2* __restrict__ xf8) {
    int tid = blockIdx.x * 256 + threadIdx.x;
    int node = tid >> 4;  // 3125 blocks exact
    int l16 = tid & 15;
    int c3 = cnt3[node];
    int c0 = c3 & 255, c1 = (c3 >> 8) & 255, c2 = (c3 >> 16) & 255;
    int tot = c0 + c1 + c2;
    float inv = 1.0f / (float)max(tot, 1);
    const int* pl = payload + (node << 6);
    float a[8] = {};
    int e = 0;
#pragma unroll 1
    for (int r = 0; r < 3; ++r) {
        int e1 = (r == 0) ? c0 : (r == 1) ? c0 + c1 : tot;
        int base = (r * NCOMBO) << 4;
        for (; e + 4 <= e1; e += 4) {
            int pA = pl[e], pB = pl[e + 1], pC = pl[e + 2], pD = pl[e + 3];
            uint2 vA = ytab8[base + ((pA >> 18) << 4) + l16];
            uint2 vB = ytab8[base + ((pB >> 18) << 4) + l16];
            uint2 vC = ytab8[base + ((pC >> 18) << 4) + l16];
            uint2 vD = ytab8[base + ((pD >> 18) << 4) + l16];
            acc8_fp8(a, vA);
            acc8_fp8(a, vB);
            acc8_fp8(a, vC);
            acc8_fp8(a, vD);
        }
        if (e + 2 <= e1) {
            int pA = pl[e], pB = pl[e + 1];
            uint2 vA = ytab8[base + ((pA >> 18) << 4) + l16];
            uint2 vB = ytab8[base + ((pB >> 18) << 4) + l16];
            acc8_fp8(a, vA);
            acc8_fp8(a, vB);
            e += 2;
        }
        if (e < e1) {
            int p = pl[e]; ++e;
            acc8_fp8(a, ytab8[base + ((p >> 18) << 4) + l16]);
        }
    }
    const float* lrow = lintab + (int)combo[node] * HID + l16 * 8;
    float v[8], s = 0.f, q = 0.f;
#pragma unroll
    for (int j = 0; j < 8; ++j) {
        v[j] = fmaf(a[j], inv, lrow[j]);
        s += v[j];
        q += v[j] * v[j];
    }
#pragma unroll
    for (int mk = 1; mk < 16; mk <<= 1) {
        s += __shfl_xor(s, mk);
        q += __shfl_xor(q, mk);
    }
    float mu = s * (1.0f / HID);
    float rstd = rsqrtf(q * (1.0f / HID) - mu * mu + LN_EPS);
    const float* g8 = lng + l16 * 8;
    const float* b8 = lnb + l16 * 8;
    float o[8];
#pragma unroll
    for (int j = 0; j < 8; ++j) o[j] = (v[j] - mu) * rstd * g8[j] + b8[j];
    uint4 w;
    w.x = packbf2(o[0], o[1]);
    w.y = packbf2(o[2], o[3]);
    w.z = packbf2(o[4], o[5]);
    w.w = packbf2(o[6], o[7]);
    xb4[(node << 4) + l16] = w;
    int lo = 0, hi = 0;
    lo = __builtin_amdgcn_cvt_pk_fp8_f32(o[0], o[1], lo, false);
    lo = __builtin_amdgcn_cvt_pk_fp8_f32(o[2], o[3], lo, true);
    hi = __builtin_amdgcn_cvt_pk_fp8_f32(o[4], o[5], hi, false);
    hi = __builtin_amdgcn_cvt_pk_fp8_f32(o[6], o[7], hi, true);
    xf8[(node << 4) + l16] = make_uint2((unsigned)lo, (unsigned)hi);
}

// ---------------------------------------------------------------------------
// LAYER 2 gather over fp8 rows (8B/lane): branch-free segments, fp32 accum,
// bf16 s_r stores. LDS-free, max occupancy (round-1 lesson).
__global__ __launch_bounds__(256) void gather3_kernel(const int* __restrict__ cnt3,
                                                      const int* __restrict__ payload,
                                                      const uint2* __restrict__ xf8,
                                                      uint4* __restrict__ s0,
                                                      uint4* __restrict__ s1,
                                                      uint4* __restrict__ s2) {
    int tid = blockIdx.x * 256 + threadIdx.x;
    int node = tid >> 4;
    int l16 = tid & 15;
    int c3 = cnt3[node];
    int c0 = c3 & 255, c1 = (c3 >> 8) & 255, c2 = (c3 >> 16) & 255;
    int tot = c0 + c1 + c2;
    float inv = 1.0f / (float)max(tot, 1);
    const int* pl = payload + (node << 6);
    int o = node * 16 + l16;
    int e = 0;
#pragma unroll 1
    for (int r = 0; r < 3; ++r) {
        int e1 = (r == 0) ? c0 : (r == 1) ? c0 + c1 : tot;
        float a[8] = {};
        for (; e + 4 <= e1; e += 4) {
            int pA = pl[e], pB = pl[e + 1], pC = pl[e + 2], pD = pl[e + 3];
            uint2 vA = xf8[((pA & 0xffff) << 4) + l16];
            uint2 vB = xf8[((pB & 0xffff) << 4) + l16];
            uint2 vC = xf8[((pC & 0xffff) << 4) + l16];
            uint2 vD = xf8[((pD & 0xffff) << 4) + l16];
            acc8_fp8(a, vA);
            acc8_fp8(a, vB);
            acc8_fp8(a, vC);
            acc8_fp8(a, vD);
        }
        if (e + 2 <= e1) {
            int pA = pl[e], pB = pl[e + 1];
            uint2 vA = xf8[((pA & 0xffff) << 4) + l16];
            uint2 vB = xf8[((pB & 0xffff) << 4) + l16];
            acc8_fp8(a, vA);
            acc8_fp8(a, vB);
            e += 2;
        }
        if (e < e1) {
            int p = pl[e]; ++e;
            acc8_fp8(a, xf8[((p & 0xffff) << 4) + l16]);
        }
        uint4 w;
        w.x = packbf2(a[0] * inv, a[1] * inv);
        w.y = packbf2(a[2] * inv, a[3] * inv);
        w.z = packbf2(a[4] * inv, a[5] * inv);
        w.w = packbf2(a[6] * inv, a[7] * inv);
        if (r == 0) s0[o] = w;
        else if (r == 1) s1[o] = w;
        else s2[o] = w;
    }
}

// ---------------------------------------------------------------------------
// Layer-2 fused GEMM+LN+pool, 32x32x16 MFMA, wave-private 32-node groups.
// R5: mat-level DOUBLE-BUFFER prefetch (bufA/bufB, 64 VGPR total — fits the
// 128-VGPR cap the allocator enforces; R3/R4's 128-VGPR areg[4][8] spilled
// to scratch, WRITE_SIZE 136 KB -> 193 MB). mat0's loads issue before the
// Wt staging (hide under the 139 KB stage); each later mat's 8 loads hide
// under the previous mat's 32 MFMAs. Each wave owns exactly one 32-node
// group (2048 wave-slots >= 1563 groups), so no group loop.
__global__ __launch_bounds__(512) void fused_layer_kernel(
    const unsigned short* __restrict__ s0, const unsigned short* __restrict__ s1,
    const unsigned short* __restrict__ s2, const unsigned short* __restrict__ xb,
    const uint4* __restrict__ wbuf, const float* __restrict__ lb,
    const float* __restrict__ lng, const float* __restrict__ lnb,
    float* __restrict__ pooled, const float* __restrict__ reg_w,
    const float* __restrict__ reg_b, float* __restrict__ out,
    int* __restrict__ done) {
    __shared__ __align__(16) unsigned short Wt[4 * HID * WT_STRIDE];  // 139264 B
    __shared__ float csh[3 * HID];
    __shared__ float pooled_sh[HID];
    __shared__ int lastFlag;

    int wave = threadIdx.x >> 6;
    int lane = threadIdx.x & 63;
    int n32 = lane & 31;
    int hf = lane >> 5;

    int g0 = wave * gridDim.x + blockIdx.x;
    bool active = g0 < NG32;
    size_t rofs = active ? ((size_t)(g0 * 32 + n32) * HID + hf * 8) : 0;

    bf16x8 bufA[8], bufB[8];
    // issue-early: mat0's 8 loads before the Wt staging (hide under stage)
    {
        const unsigned short* p0 = s0 + rofs;
#pragma unroll
        for (int t = 0; t < 8; ++t) bufA[t] = *(const bf16x8*)(p0 + t * 16);
    }

    if (threadIdx.x < HID) {
        pooled_sh[threadIdx.x] = 0.0f;
        csh[threadIdx.x] = lb[threadIdx.x];
        csh[HID + threadIdx.x] = lng[threadIdx.x];
        csh[2 * HID + threadIdx.x] = lnb[threadIdx.x];
    }
    uint4* wt4 = (uint4*)Wt;
#pragma unroll
    for (int i = 0; i < 17; ++i)
        wt4[i * 512 + threadIdx.x] = wbuf[i * 512 + threadIdx.x];
    __syncthreads();

    float pacc[4] = {0.f, 0.f, 0.f, 0.f};

    if (active) {
        f32x16 acc[4];
#pragma unroll
        for (int ct = 0; ct < 4; ++ct)
#pragma unroll
            for (int i = 0; i < 16; ++i) acc[ct][i] = 0.0f;

        const unsigned short* wbase = Wt + n32 * WT_STRIDE + hf * 8;

        // domat: consume 8 fragments of `buf` against weight mat `m`
#define DOMAT(buf, m)                                                          \
        {                                                                      \
            const unsigned short* wm = wbase + (m) * (HID * WT_STRIDE);        \
            _Pragma("unroll")                                                  \
            for (int t = 0; t < 8; ++t) {                                      \
                _Pragma("unroll")                                              \
                for (int ct = 0; ct < 4; ++ct) {                               \
                    bf16x8 bfr = *(const bf16x8*)(wm + ct * 32 * WT_STRIDE + t * 16); \
                    acc[ct] = __builtin_amdgcn_mfma_f32_32x32x16_bf16(         \
                        buf[t], bfr, acc[ct], 0, 0, 0);                        \
                }                                                              \
            }                                                                  \
        }
#define LDMAT(buf, srcp)                                                       \
        {                                                                      \
            const unsigned short* _p = (srcp) + rofs;                          \
            _Pragma("unroll")                                                  \
            for (int t = 0; t < 8; ++t) buf[t] = *(const bf16x8*)(_p + t * 16);\
        }

        LDMAT(bufB, s1);   // issue mat1 loads
        DOMAT(bufA, 0);    // compute mat0 (hides mat1 latency)
        LDMAT(bufA, s2);   // issue mat2
        DOMAT(bufB, 1);
        LDMAT(bufB, xb);   // issue mat3
        DOMAT(bufA, 2);
        DOMAT(bufB, 3);
#undef DOMAT
#undef LDMAT

        int node0 = g0 * 32;
#pragma unroll
        for (int reg = 0; reg < 16; ++reg) {
            int row = node0 + (reg & 3) + 8 * (reg >> 2) + 4 * hf;
            float v[4];
            float s = 0.f, q = 0.f;
#pragma unroll
            for (int ct = 0; ct < 4; ++ct) {
                v[ct] = acc[ct][reg] + csh[ct * 32 + n32];
                s += v[ct];
                q += v[ct] * v[ct];
            }
#pragma unroll
            for (int mk = 1; mk < 32; mk <<= 1) {
                s += __shfl_xor(s, mk);
                q += __shfl_xor(q, mk);
            }
            float mu = s * (1.0f / HID);
            float rstd = rsqrtf(q * (1.0f / HID) - mu * mu + LN_EPS);
            if (row < N_NODES) {
#pragma unroll
                for (int ct = 0; ct < 4; ++ct) {
                    int col = ct * 32 + n32;
                    pacc[ct] += (v[ct] - mu) * rstd * csh[HID + col] + csh[2 * HID + col];
                }
            }
        }
    }

#pragma unroll
    for (int ct = 0; ct < 4; ++ct) {
        float t = pacc[ct] + __shfl_xor(pacc[ct], 32);
        if (hf == 0) atomicAdd(&pooled_sh[ct * 32 + n32], t);
    }
    __syncthreads();
    if (threadIdx.x < HID) atomicAdd(&pooled[threadIdx.x], pooled_sh[threadIdx.x]);

    // ---- folded final reduction (last block) ----
    __threadfence();
    __syncthreads();
    if (threadIdx.x == 0)
        lastFlag = (atomicAdd(done, 1) == (int)gridDim.x - 1);
    __syncthreads();
    if (lastFlag && threadIdx.x < 64) {
        int l = threadIdx.x;
        // atomic fetch-add(0) reads take the same coherent path as the writes
        float s = atomicAdd(&pooled[l], 0.0f) * reg_w[l] +
                  atomicAdd(&pooled[64 + l], 0.0f) * reg_w[64 + l];
#pragma unroll
        for (int o = 32; o; o >>= 1) s += __shfl_down(s, o);
        if (l == 0) out[0] = s * (1.0f / N_NODES) + reg_b[0];
    }
}

// ---------------------------------------------------------------------------
extern "C" void kernel_launch(void* const* d_in, const int* in_sizes, int n_in,
                              void* d_out, int out_size, void* d_ws, size_t ws_size,
                              hipStream_t stream) {
    const int* z = (const int*)d_in[0];
    const int* nt = (const int*)d_in[1];
    const int* ei = (const int*)d_in[2];
    const int* et = (const int*)d_in[3];
    const float* z_embed = (const float*)d_in[4];
    const float* enc_w1 = (const float*)d_in[5];
    const float* enc_b1 = (const float*)d_in[6];
    const float* enc_w2 = (const float*)d_in[7];
    const float* enc_b2 = (const float*)d_in[8];
    const float* lin_w = (const float*)d_in[9];
    const float* lin_b = (const float*)d_in[10];
    const float* rel_w = (const float*)d_in[11];
    const float* ln_g = (const float*)d_in[12];
    const float* ln_b = (const float*)d_in[13];
    const float* reg_w = (const float*)d_in[14];
    const float* reg_b = (const float*)d_in[15];
    float* out = (float*)d_out;

    const size_t NHb = (size_t)NROWS * HID;
    char* p = (char*)d_ws;
    unsigned short* xb = (unsigned short*)p;    p += NHb * 2;
    unsigned short* s0 = (unsigned short*)p;    p += NHb * 2;
    unsigned short* s1 = (unsigned short*)p;    p += NHb * 2;
    unsigned short* s2 = (unsigned short*)p;    p += NHb * 2;
    uint2* xf8 = (uint2*)p;                     p += NHb;      // fp8 copy, 6.4 MB
    unsigned short* wbuf = (unsigned short*)p;  p += (size_t)4 * HID * WT_STRIDE * 2;
    unsigned int* ytab = (unsigned int*)p;      p += (size_t)N_REL * NCOMBO * HID;  // fp8
    float* lintab = (float*)p;                  p += NCOMBO * HID * 4;
    unsigned short* combo = (unsigned short*)p; p += N_NODES * 2;
    float* pooled = (float*)p;                  p += HID * 4;
    int* cnt3 = (int*)p;                        p += N_NODES * 4;
    int* bcnt = (int*)p;                        p += NBKT * 4;
    int* done = (int*)p;                        p += 4;        // adjacent to bcnt
    int* bucket = (int*)p;                      p += (size_t)NBKT * CAP1 * 4;
    int* payload = (int*)p;                     p += (size_t)N_NODES * CAP * 4;

    const int* src = ei;
    const int* dst = ei + N_EDGES;

    hipMemsetAsync(bcnt, 0, (NBKT + 1) * sizeof(int), stream);  // bcnt + done

    // front-end: edge binning || encoder tables || weight prep (one dispatch)
    build_tables_kernel<<<NBKT + NCOMBO + 256, 256, 0, stream>>>(
        src, dst, et, z, nt, z_embed, enc_w1, enc_b1, enc_w2, enc_b2,
        rel_w, lin_w, lin_b, combo, bcnt, bucket, ytab, lintab, wbuf, pooled);

    build2_kernel<<<NBKT, 256, 0, stream>>>(bcnt, bucket, combo, cnt3, payload);

    // layer 1: fused fp8 table-gather + lin + LN -> xb (bf16) + xf8 (fp8)
    gather_ln1_kernel<<<3125, 256, 0, stream>>>(cnt3, payload, (const uint2*)ytab, lintab,
                                                combo, ln_g, ln_b, (uint4*)xb, xf8);
    // layer 2: fp8 branch-free gather + MFMA fused layer (pool + final fold)
    gather3_kernel<<<3125, 256, 0, stream>>>(cnt3, payload, xf8,
                                             (uint4*)s0, (uint4*)s1, (uint4*)s2);
    fused_layer_kernel<<<256, 512, 0, stream>>>(
        s0, s1, s2, xb, (const uint4*)wbuf, lin_b + HID, ln_g + HID, ln_b + HID,
        pooled, reg_w, reg_b, out, done);
}